// Round 7
// baseline (81.745 us; speedup 1.0000x reference)
//
#include <hip/hip_runtime.h>
#include <cstdint>

#define NCLS 13
#define SMAX 10
#define PTHRESH 0.05f
#define FPS_SEG 8        // blocks per (b,c)
#define FPS_T 512        // threads per FPS block (8 waves)
#define FPS_PPT 16       // points per thread: 8*512*16 = 65536
#define NSLOT 64         // publisher waves per (b,c) = FPS_SEG * FPS_T/64
#define GABLK 256        // k_setup blocks per batch (N/256)
#define BB 2             // batch
#define SLOT_DWORDS (BB * NCLS * SMAX * NSLOT * 2)

// Exact (un-fused) squared distance, matching numpy's ((dx*dx + dy*dy) + dz*dz) in f32.
__device__ __forceinline__ float d2f(float ax, float ay, float az,
                                     float bx, float by, float bz) {
    float dx = ax - bx;
    float dy = ay - by;
    float dz = az - bz;
    return __fadd_rn(__fadd_rn(__fmul_rn(dx, dx), __fmul_rn(dy, dy)), __fmul_rn(dz, dz));
}

// Monotone mapping float -> uint32. Never 0 for non-NaN input => key==0 means "empty".
__device__ __forceinline__ unsigned int fmono(float f) {
    unsigned int u = __float_as_uint(f);
    return (u & 0x80000000u) ? ~u : (u | 0x80000000u);
}

// Kernel A: class softmax, shifted coords (SoA), PER-BLOCK partial counts/first-index
// (full overwrite -> no zero-init, no global atomics), plus zeroing the FPS slots.
__global__ void k_setup(const float* __restrict__ logits, const float* __restrict__ pts,
                        const float* __restrict__ offs, float* __restrict__ probs,
                        float* __restrict__ sx, float* __restrict__ sy, float* __restrict__ sz,
                        unsigned int* __restrict__ pcnt, unsigned int* __restrict__ pfst,
                        unsigned int* __restrict__ slots32, int N) {
    int b = blockIdx.y;
    int n = blockIdx.x * blockDim.x + threadIdx.x;
    int t = threadIdx.x;
    __shared__ unsigned int sC[NCLS], sF[NCLS];
    if (t < NCLS) { sC[t] = 0u; sF[t] = 0xFFFFFFFFu; }
    __syncthreads();

    // zero FPS slots (every call: graph replays leave stale nonzero keys behind)
    if (b == 0) {
        for (unsigned int i = blockIdx.x * blockDim.x + t; i < SLOT_DWORDS;
             i += GABLK * 256)
            slots32[i] = 0u;
    }

    if (n < N) {
        size_t bn = (size_t)b * N + n;
        const float* L = logits + bn * NCLS;
        float v[NCLS];
        float mx = -INFINITY;
#pragma unroll
        for (int c = 0; c < NCLS; ++c) { v[c] = L[c]; mx = fmaxf(mx, v[c]); }
        float s = 0.f;
#pragma unroll
        for (int c = 0; c < NCLS; ++c) { v[c] = expf(v[c] - mx); s += v[c]; }
        int lane = t & 63;
        int wave_base = n - lane;
#pragma unroll
        for (int c = 0; c < NCLS; ++c) {
            float p = v[c] / s;
            probs[((size_t)b * NCLS + c) * N + n] = p;
            unsigned long long m = __ballot(p > PTHRESH);
            if (lane == 0 && m) {
                atomicAdd(&sC[c], (unsigned int)__popcll(m));
                atomicMin(&sF[c], (unsigned int)(wave_base + __ffsll(m) - 1));
            }
        }
        float x = pts[bn * 3 + 0] + offs[bn * 3 + 0];
        float y = pts[bn * 3 + 1] + offs[bn * 3 + 1];
        float z = pts[bn * 3 + 2] + offs[bn * 3 + 2];
        sx[bn] = x; sy[bn] = y; sz[bn] = z;
    }
    __syncthreads();
    if (t < NCLS) {
        pcnt[(b * NCLS + t) * GABLK + blockIdx.x] = sC[t];
        pfst[(b * NCLS + t) * GABLK + blockIdx.x] = sF[t];
    }
}

// Kernel B: deterministic FPS, wave-autonomous. 8 blocks x 8 waves per (b,c) = 64
// publisher waves; slots per (bc,step) = 64 u64 (one per lane of the polling wave).
// Per step: thread partial argmax -> 64-lane butterfly -> lane0 relaxed-store own slot
// -> every lane relaxed-polls its slot (no buffer_inv) -> butterfly max = winner.
// No __syncthreads, no LDS, no fences: the u64 key is pure value communication.
// asm "+v" pins X/Y/Z/m in VGPRs: without it the compiler REMATERIALIZES the coord
// loads every step (rounds 4-6: VGPR=60, 48 L2 reloads/thread/step on the critical
// path). launch_bounds(FPS_T,1) provides the register budget (~110 live < 256 cap).
__global__ __launch_bounds__(FPS_T, 1) void k_fps(
    const float* __restrict__ probs,
    const float* __restrict__ sx, const float* __restrict__ sy, const float* __restrict__ sz,
    const unsigned int* __restrict__ pcnt, const unsigned int* __restrict__ pfst,
    int* __restrict__ nseeds, float* __restrict__ seedxyz,
    unsigned long long* __restrict__ slots, int N) {
    int g = blockIdx.x;
    int c = blockIdx.y;
    int b = blockIdx.z;
    int bc = b * NCLS + c;
    int t = threadIdx.x, lane = t & 63, w = t >> 6;

    // Reduce per-block partials (each wave redundantly; identical ops -> identical result)
    const unsigned int* pc = pcnt + (size_t)bc * GABLK;
    const unsigned int* pf = pfst + (size_t)bc * GABLK;
    uint4 c4 = *(const uint4*)(pc + lane * 4);
    uint4 f4 = *(const uint4*)(pf + lane * 4);
    unsigned int cnt = c4.x + c4.y + c4.z + c4.w;
    unsigned int fst = min(min(f4.x, f4.y), min(f4.z, f4.w));
#pragma unroll
    for (int off = 1; off < 64; off <<= 1) {
        cnt += __shfl_xor(cnt, off, 64);
        fst = min(fst, __shfl_xor(fst, off, 64));
    }
    int ns = min(SMAX, min((int)cnt / 50, (int)cnt));
    if (g == 0 && t == 0) nseeds[bc] = ns;
    if (ns == 0) return;

    const float* px = sx + (size_t)b * N;
    const float* py = sy + (size_t)b * N;
    const float* pz = sz + (size_t)b * N;
    const float* pp = probs + (size_t)bc * N;

    int base = g * (FPS_T * FPS_PPT) + t;
    float X[FPS_PPT], Y[FPS_PPT], Z[FPS_PPT], m[FPS_PPT];
    unsigned int vm = 0;
#pragma unroll
    for (int j = 0; j < FPS_PPT; ++j) {
        int n = base + (j << 9);
        X[j] = px[n]; Y[j] = py[n]; Z[j] = pz[n];
        if (pp[n] > PTHRESH) vm |= (1u << j);
        m[j] = INFINITY;
    }
    // Pin state in registers: values become asm outputs -> not rematerializable.
#pragma unroll
    for (int j = 0; j < FPS_PPT; ++j) {
        asm volatile("" : "+v"(X[j]), "+v"(Y[j]), "+v"(Z[j]), "+v"(m[j]));
    }

    int st = (int)fst;
    float cx = px[st], cy = py[st], cz = pz[st];
    if (g == 0 && t == 0) {
        float* sd = seedxyz + (size_t)bc * SMAX * 3;
        sd[0] = cx; sd[1] = cy; sd[2] = cz;
    }

    for (int s = 1; s < ns; ++s) {
        float best = -INFINITY;
        int bidx = 0;
#pragma unroll
        for (int j = 0; j < FPS_PPT; ++j) {   // ascending n => first-occurrence tiebreak
            int n = base + (j << 9);
            float d2 = d2f(X[j], Y[j], Z[j], cx, cy, cz);
            float add = ((vm >> j) & 1u) ? 0.0f : -INFINITY;
            float nm = fminf(m[j], __fadd_rn(d2, add));
            m[j] = nm;
            if (nm > best) { best = nm; bidx = n; }
        }
        unsigned long long key =
            ((unsigned long long)fmono(best) << 32) | (unsigned int)(~(unsigned int)bidx);
#pragma unroll
        for (int off = 1; off < 64; off <<= 1) {
            unsigned long long ok = __shfl_xor(key, off, 64);
            if (ok > key) key = ok;
        }
        unsigned long long* sl = slots + ((size_t)bc * SMAX + s) * NSLOT;
        if (lane == 0)
            __hip_atomic_store(&sl[g * (FPS_T / 64) + w], key,
                               __ATOMIC_RELAXED, __HIP_MEMORY_SCOPE_AGENT);
        asm volatile("" ::: "memory");   // pin publish before poll (no runtime cost)
        unsigned long long k = 0ULL;
        while (true) {
            if (k == 0ULL)
                k = __hip_atomic_load(&sl[lane], __ATOMIC_RELAXED, __HIP_MEMORY_SCOPE_AGENT);
            if (__all(k != 0ULL)) break;
        }
        asm volatile("" ::: "memory");
#pragma unroll
        for (int off = 1; off < 64; off <<= 1) {
            unsigned long long ok = __shfl_xor(k, off, 64);
            if (ok > k) k = ok;
        }
        int widx = (int)(~(unsigned int)k);
        cx = px[widx]; cy = py[widx]; cz = pz[widx];
        if (g == 0 && t == 0) {
            float* sd = seedxyz + ((size_t)bc * SMAX + s) * 3;
            sd[0] = cx; sd[1] = cy; sd[2] = cz;
        }
    }
}

// Kernel C: 512-thread block owns 64 points. Wave w (lane=point) handles classes
// {w, w+8} in pass 1 (gd + partial sumexp -> LDS), rows k==w (mod 8) in pass 2.
__global__ __launch_bounds__(512) void k_out(
    const float* __restrict__ probs,
    const float* __restrict__ sx, const float* __restrict__ sy,
    const float* __restrict__ sz,
    const int* __restrict__ nseeds, const float* __restrict__ seedxyz,
    float* __restrict__ out, int N) {
    int b = blockIdx.y;
    int t = threadIdx.x;
    int lane = t & 63;       // point within 64-point tile
    int wv = t >> 6;         // wave 0..7
    int n = blockIdx.x * 64 + lane;

    __shared__ float S[NCLS * SMAX * 3];
    __shared__ int NSs[NCLS];
    __shared__ float gdS[NCLS][64];
    __shared__ float psum[8][64];
    if (t < NCLS * SMAX * 3) S[t] = seedxyz[(size_t)b * NCLS * SMAX * 3 + t];
    if (t >= 448 && t < 448 + NCLS) NSs[t - 448] = nseeds[b * NCLS + (t - 448)];
    __syncthreads();

    size_t bn = (size_t)b * N + n;
    float x = sx[bn], y = sy[bn], z = sz[bn];

    const float kinv = 22.2222222f;   // 1/0.045
    float ps = 0.f;
#pragma unroll
    for (int c = wv; c < NCLS; c += 8) {
        int ns = NSs[c];
        float gdv = 0.f;
        if (ns > 0) {
            float pv = probs[((size_t)b * NCLS + c) * N + n];
            if (pv > PTHRESH) {
                float wbuf[SMAX];
                float sw = 0.f;
#pragma unroll
                for (int s = 0; s < SMAX; ++s) {
                    wbuf[s] = 0.f;
                    if (s < ns) {
                        const float* sd = &S[(c * SMAX + s) * 3];
                        float d2 = d2f(x, y, z, sd[0], sd[1], sd[2]);
                        wbuf[s] = __expf(-d2 * kinv);
                        sw += wbuf[s];
                    }
                }
                gdv = __fdividef(pv, sw + 1e-8f);
#pragma unroll
                for (int s = 0; s < SMAX; ++s)
                    if (s < ns) ps += __expf(10.f * wbuf[s] * gdv);
            } else {
                ps += (float)ns;   // exp(0)=1 per valid seed, exact
            }
        }
        gdS[c][lane] = gdv;
    }
    psum[wv][lane] = ps;
    __syncthreads();

    float tot = 0.f;
#pragma unroll
    for (int w = 0; w < 8; ++w) tot += psum[w][lane];
    float inv = __fdividef(1.f, tot);

    float* ob = out + (size_t)b * (NCLS * SMAX) * N + n;
#pragma unroll
    for (int k = 0; k < NCLS * SMAX; k += 8) {
        int kk = k + wv;
        if (kk >= NCLS * SMAX) break;
        int c = kk / SMAX, s = kk - c * SMAX;
        float o = 0.f;
        if (s < NSs[c]) {
            float gdv = gdS[c][lane];
            if (gdv > 0.f) {
                const float* sd = &S[(c * SMAX + s) * 3];
                float d2 = d2f(x, y, z, sd[0], sd[1], sd[2]);
                float wval = __expf(-d2 * kinv);
                o = __expf(10.f * wval * gdv) * inv;
            } else {
                o = inv;
            }
        }
        ob[(size_t)kk * N] = o;
    }
}

extern "C" void kernel_launch(void* const* d_in, const int* in_sizes, int n_in,
                              void* d_out, int out_size, void* d_ws, size_t ws_size,
                              hipStream_t stream) {
    const float* logits = (const float*)d_in[0];
    const float* pts    = (const float*)d_in[1];
    const float* offs   = (const float*)d_in[2];
    float* out = (float*)d_out;

    const int B = BB;
    const int BN = in_sizes[0] / NCLS;   // B*N
    const int N = BN / B;                // 65536

    // Workspace layout
    char* w = (char*)d_ws;
    size_t off = 0;
    auto take = [&](size_t bytes) -> void* {
        void* p = w + off;
        off = (off + bytes + 255) & ~(size_t)255;
        return p;
    };
    float* probs   = (float*)take((size_t)B * NCLS * N * sizeof(float));
    float* sx      = (float*)take((size_t)B * N * sizeof(float));
    float* sy      = (float*)take((size_t)B * N * sizeof(float));
    float* sz      = (float*)take((size_t)B * N * sizeof(float));
    float* seedxyz = (float*)take((size_t)B * NCLS * SMAX * 3 * sizeof(float));
    unsigned int* pcnt = (unsigned int*)take((size_t)B * NCLS * GABLK * sizeof(unsigned int));
    unsigned int* pfst = (unsigned int*)take((size_t)B * NCLS * GABLK * sizeof(unsigned int));
    int* nseeds        = (int*)take(B * NCLS * sizeof(int));
    unsigned long long* slots =
        (unsigned long long*)take((size_t)B * NCLS * SMAX * NSLOT * sizeof(unsigned long long));

    dim3 gA((N + 255) / 256, B);   // == (GABLK, B)
    k_setup<<<gA, 256, 0, stream>>>(logits, pts, offs, probs, sx, sy, sz,
                                    pcnt, pfst, (unsigned int*)slots, N);

    dim3 gB(FPS_SEG, NCLS, B);
    k_fps<<<gB, FPS_T, 0, stream>>>(probs, sx, sy, sz, pcnt, pfst, nseeds, seedxyz,
                                    slots, N);

    dim3 gC(N / 64, B);
    k_out<<<gC, 512, 0, stream>>>(probs, sx, sy, sz, nseeds, seedxyz, out, N);
}

// Round 8
// 65.731 us; speedup vs baseline: 1.2436x; 1.2436x over previous
//
#include <hip/hip_runtime.h>
#include <cstdint>

#define NCLS 13
#define SMAX 10
#define PTHRESH 0.05f
#define FPS_SEG 8        // blocks per (b,c)
#define FPS_T 512        // threads per FPS block (8 waves)
#define FPS_PPT 16       // points per thread: 8*512*16 = 65536
#define NSLOT 8          // one record per block per step
#define BCPAD 32         // padded bc dim: all 8 blocks of a bc share bid%32 -> same XCD residue
#define GABLK 256        // k_setup blocks per batch (N/256)
#define BB 2             // batch
#define SLOT_DWORDS (BB * NCLS * SMAX * NSLOT * 2)

// Exact (un-fused) squared distance, matching numpy's ((dx*dx + dy*dy) + dz*dz) in f32.
__device__ __forceinline__ float d2f(float ax, float ay, float az,
                                     float bx, float by, float bz) {
    float dx = ax - bx;
    float dy = ay - by;
    float dz = az - bz;
    return __fadd_rn(__fadd_rn(__fmul_rn(dx, dx), __fmul_rn(dy, dy)), __fmul_rn(dz, dz));
}

// Monotone mapping float -> uint32. Never 0 for non-NaN input => key==0 means "empty".
__device__ __forceinline__ unsigned int fmono(float f) {
    unsigned int u = __float_as_uint(f);
    return (u & 0x80000000u) ? ~u : (u | 0x80000000u);
}

// Kernel A: class softmax, shifted coords (SoA), PER-BLOCK partial counts/first-index
// (full overwrite -> no zero-init, no global atomics), plus zeroing the FPS slots.
__global__ void k_setup(const float* __restrict__ logits, const float* __restrict__ pts,
                        const float* __restrict__ offs, float* __restrict__ probs,
                        float* __restrict__ sx, float* __restrict__ sy, float* __restrict__ sz,
                        unsigned int* __restrict__ pcnt, unsigned int* __restrict__ pfst,
                        unsigned int* __restrict__ slots32, int N) {
    int b = blockIdx.y;
    int n = blockIdx.x * blockDim.x + threadIdx.x;
    int t = threadIdx.x;
    __shared__ unsigned int sC[NCLS], sF[NCLS];
    if (t < NCLS) { sC[t] = 0u; sF[t] = 0xFFFFFFFFu; }
    __syncthreads();

    // zero FPS slots (every call: graph replays leave stale nonzero keys behind)
    if (b == 0) {
        for (unsigned int i = blockIdx.x * blockDim.x + t; i < SLOT_DWORDS;
             i += GABLK * 256)
            slots32[i] = 0u;
    }

    if (n < N) {
        size_t bn = (size_t)b * N + n;
        const float* L = logits + bn * NCLS;
        float v[NCLS];
        float mx = -INFINITY;
#pragma unroll
        for (int c = 0; c < NCLS; ++c) { v[c] = L[c]; mx = fmaxf(mx, v[c]); }
        float s = 0.f;
#pragma unroll
        for (int c = 0; c < NCLS; ++c) { v[c] = expf(v[c] - mx); s += v[c]; }
        int lane = t & 63;
        int wave_base = n - lane;
#pragma unroll
        for (int c = 0; c < NCLS; ++c) {
            float p = v[c] / s;
            probs[((size_t)b * NCLS + c) * N + n] = p;
            unsigned long long m = __ballot(p > PTHRESH);
            if (lane == 0 && m) {
                atomicAdd(&sC[c], (unsigned int)__popcll(m));
                atomicMin(&sF[c], (unsigned int)(wave_base + __ffsll(m) - 1));
            }
        }
        float x = pts[bn * 3 + 0] + offs[bn * 3 + 0];
        float y = pts[bn * 3 + 1] + offs[bn * 3 + 1];
        float z = pts[bn * 3 + 2] + offs[bn * 3 + 2];
        sx[bn] = x; sy[bn] = y; sz[bn] = z;
    }
    __syncthreads();
    if (t < NCLS) {
        pcnt[(b * NCLS + t) * GABLK + blockIdx.x] = sC[t];
        pfst[(b * NCLS + t) * GABLK + blockIdx.x] = sF[t];
    }
}

// Kernel B: deterministic FPS. 8 blocks x 512 threads per (b,c). Per step:
// wave butterfly argmax -> LDS -> barrier -> wave0 reduces 8 keys -> lane0 publishes
// ONE record per block (8 slots = one 64B line per bc,step) -> lanes 0-7 of wave0
// poll with s_sleep backoff (one coalesced line request per iteration) -> winner via
// LDS broadcast + barrier. Poll traffic ~500x lower than the all-thread tight spin
// (rounds 4-7: 4096 pollers/bc congested the coherence point, ~4.3us/step).
__global__ __launch_bounds__(FPS_T, 1) void k_fps(
    const float* __restrict__ probs,
    const float* __restrict__ sx, const float* __restrict__ sy, const float* __restrict__ sz,
    const unsigned int* __restrict__ pcnt, const unsigned int* __restrict__ pfst,
    int* __restrict__ nseeds, float* __restrict__ seedxyz,
    unsigned long long* __restrict__ slots, int N) {
    int bid = blockIdx.x;
    int bc = bid & (BCPAD - 1);   // all 8 segments of a bc share bid%32 (same XCD residue)
    int g = bid >> 5;             // segment 0..7
    if (bc >= BB * NCLS) return;  // padding blocks
    int b = bc / NCLS;
    int t = threadIdx.x, lane = t & 63, w = t >> 6;

    // Reduce per-block partials (each wave redundantly; identical ops -> identical result)
    const unsigned int* pc = pcnt + (size_t)bc * GABLK;
    const unsigned int* pf = pfst + (size_t)bc * GABLK;
    uint4 c4 = *(const uint4*)(pc + lane * 4);
    uint4 f4 = *(const uint4*)(pf + lane * 4);
    unsigned int cnt = c4.x + c4.y + c4.z + c4.w;
    unsigned int fst = min(min(f4.x, f4.y), min(f4.z, f4.w));
#pragma unroll
    for (int off = 1; off < 64; off <<= 1) {
        cnt += __shfl_xor(cnt, off, 64);
        fst = min(fst, __shfl_xor(fst, off, 64));
    }
    int ns = min(SMAX, min((int)cnt / 50, (int)cnt));
    if (g == 0 && t == 0) nseeds[bc] = ns;
    if (ns == 0) return;

    const float* px = sx + (size_t)b * N;
    const float* py = sy + (size_t)b * N;
    const float* pz = sz + (size_t)b * N;
    const float* pp = probs + (size_t)bc * N;

    int base = g * (FPS_T * FPS_PPT) + t;
    float X[FPS_PPT], Y[FPS_PPT], Z[FPS_PPT], m[FPS_PPT];
    unsigned int vm = 0;
#pragma unroll
    for (int j = 0; j < FPS_PPT; ++j) {
        int n = base + (j << 9);
        X[j] = px[n]; Y[j] = py[n]; Z[j] = pz[n];
        if (pp[n] > PTHRESH) vm |= (1u << j);
        m[j] = INFINITY;
    }

    int st = (int)fst;
    float cx = px[st], cy = py[st], cz = pz[st];
    if (g == 0 && t == 0) {
        float* sd = seedxyz + (size_t)bc * SMAX * 3;
        sd[0] = cx; sd[1] = cy; sd[2] = cz;
    }

    __shared__ unsigned long long s_keys[FPS_T / 64];
    __shared__ unsigned long long s_win;

    for (int s = 1; s < ns; ++s) {
        float best = -INFINITY;
        int bidx = 0;
#pragma unroll
        for (int j = 0; j < FPS_PPT; ++j) {   // ascending n => first-occurrence tiebreak
            int n = base + (j << 9);
            float d2 = d2f(X[j], Y[j], Z[j], cx, cy, cz);
            float add = ((vm >> j) & 1u) ? 0.0f : -INFINITY;
            float nm = fminf(m[j], __fadd_rn(d2, add));
            m[j] = nm;
            if (nm > best) { best = nm; bidx = n; }
        }
        unsigned long long key =
            ((unsigned long long)fmono(best) << 32) | (unsigned int)(~(unsigned int)bidx);
#pragma unroll
        for (int off = 1; off < 64; off <<= 1) {
            unsigned long long ok = __shfl_xor(key, off, 64);
            if (ok > key) key = ok;
        }
        if (lane == 0) s_keys[w] = key;
        __syncthreads();

        if (w == 0) {
            // block-level reduce of the 8 wave keys (lanes 0-7)
            unsigned long long bk = (lane < 8) ? s_keys[lane] : 0ULL;
#pragma unroll
            for (int off = 1; off < 8; off <<= 1) {
                unsigned long long ok = __shfl_xor(bk, off, 8);
                if (ok > bk) bk = ok;
            }
            unsigned long long* sl = slots + ((size_t)bc * SMAX + s) * NSLOT;
            if (lane == 0)
                __hip_atomic_store(&sl[g], bk, __ATOMIC_RELAXED, __HIP_MEMORY_SCOPE_AGENT);
            asm volatile("" ::: "memory");
            unsigned long long kk = 0ULL;
            while (true) {
                if (lane < NSLOT && kk == 0ULL)
                    kk = __hip_atomic_load(&sl[lane], __ATOMIC_RELAXED,
                                           __HIP_MEMORY_SCOPE_AGENT);
                if (__all(kk != 0ULL || lane >= NSLOT)) break;
                __builtin_amdgcn_s_sleep(1);
            }
            asm volatile("" ::: "memory");
#pragma unroll
            for (int off = 1; off < 8; off <<= 1) {
                unsigned long long ok = __shfl_xor(kk, off, 8);
                if (ok > kk) kk = ok;
            }
            if (lane == 0) s_win = kk;
        }
        __syncthreads();

        int widx = (int)(~(unsigned int)s_win);
        cx = px[widx]; cy = py[widx]; cz = pz[widx];
        if (g == 0 && t == 0) {
            float* sd = seedxyz + ((size_t)bc * SMAX + s) * 3;
            sd[0] = cx; sd[1] = cy; sd[2] = cz;
        }
        __syncthreads();   // protect s_win until everyone has read it
    }
}

// Kernel C: 512-thread block owns 64 points. Wave w (lane=point) handles classes
// {w, w+8} in pass 1 (gd + partial sumexp -> LDS), rows k==w (mod 8) in pass 2.
__global__ __launch_bounds__(512) void k_out(
    const float* __restrict__ probs,
    const float* __restrict__ sx, const float* __restrict__ sy,
    const float* __restrict__ sz,
    const int* __restrict__ nseeds, const float* __restrict__ seedxyz,
    float* __restrict__ out, int N) {
    int b = blockIdx.y;
    int t = threadIdx.x;
    int lane = t & 63;       // point within 64-point tile
    int wv = t >> 6;         // wave 0..7
    int n = blockIdx.x * 64 + lane;

    __shared__ float S[NCLS * SMAX * 3];
    __shared__ int NSs[NCLS];
    __shared__ float gdS[NCLS][64];
    __shared__ float psum[8][64];
    if (t < NCLS * SMAX * 3) S[t] = seedxyz[(size_t)b * NCLS * SMAX * 3 + t];
    if (t >= 448 && t < 448 + NCLS) NSs[t - 448] = nseeds[b * NCLS + (t - 448)];
    __syncthreads();

    size_t bn = (size_t)b * N + n;
    float x = sx[bn], y = sy[bn], z = sz[bn];

    const float kinv = 22.2222222f;   // 1/0.045
    float ps = 0.f;
#pragma unroll
    for (int c = wv; c < NCLS; c += 8) {
        int ns = NSs[c];
        float gdv = 0.f;
        if (ns > 0) {
            float pv = probs[((size_t)b * NCLS + c) * N + n];
            if (pv > PTHRESH) {
                float wbuf[SMAX];
                float sw = 0.f;
#pragma unroll
                for (int s = 0; s < SMAX; ++s) {
                    wbuf[s] = 0.f;
                    if (s < ns) {
                        const float* sd = &S[(c * SMAX + s) * 3];
                        float d2 = d2f(x, y, z, sd[0], sd[1], sd[2]);
                        wbuf[s] = __expf(-d2 * kinv);
                        sw += wbuf[s];
                    }
                }
                gdv = __fdividef(pv, sw + 1e-8f);
#pragma unroll
                for (int s = 0; s < SMAX; ++s)
                    if (s < ns) ps += __expf(10.f * wbuf[s] * gdv);
            } else {
                ps += (float)ns;   // exp(0)=1 per valid seed, exact
            }
        }
        gdS[c][lane] = gdv;
    }
    psum[wv][lane] = ps;
    __syncthreads();

    float tot = 0.f;
#pragma unroll
    for (int w = 0; w < 8; ++w) tot += psum[w][lane];
    float inv = __fdividef(1.f, tot);

    float* ob = out + (size_t)b * (NCLS * SMAX) * N + n;
#pragma unroll
    for (int k = 0; k < NCLS * SMAX; k += 8) {
        int kk = k + wv;
        if (kk >= NCLS * SMAX) break;
        int c = kk / SMAX, s = kk - c * SMAX;
        float o = 0.f;
        if (s < NSs[c]) {
            float gdv = gdS[c][lane];
            if (gdv > 0.f) {
                const float* sd = &S[(c * SMAX + s) * 3];
                float d2 = d2f(x, y, z, sd[0], sd[1], sd[2]);
                float wval = __expf(-d2 * kinv);
                o = __expf(10.f * wval * gdv) * inv;
            } else {
                o = inv;
            }
        }
        ob[(size_t)kk * N] = o;
    }
}

extern "C" void kernel_launch(void* const* d_in, const int* in_sizes, int n_in,
                              void* d_out, int out_size, void* d_ws, size_t ws_size,
                              hipStream_t stream) {
    const float* logits = (const float*)d_in[0];
    const float* pts    = (const float*)d_in[1];
    const float* offs   = (const float*)d_in[2];
    float* out = (float*)d_out;

    const int B = BB;
    const int BN = in_sizes[0] / NCLS;   // B*N
    const int N = BN / B;                // 65536

    // Workspace layout
    char* w = (char*)d_ws;
    size_t off = 0;
    auto take = [&](size_t bytes) -> void* {
        void* p = w + off;
        off = (off + bytes + 255) & ~(size_t)255;
        return p;
    };
    float* probs   = (float*)take((size_t)B * NCLS * N * sizeof(float));
    float* sx      = (float*)take((size_t)B * N * sizeof(float));
    float* sy      = (float*)take((size_t)B * N * sizeof(float));
    float* sz      = (float*)take((size_t)B * N * sizeof(float));
    float* seedxyz = (float*)take((size_t)B * NCLS * SMAX * 3 * sizeof(float));
    unsigned int* pcnt = (unsigned int*)take((size_t)B * NCLS * GABLK * sizeof(unsigned int));
    unsigned int* pfst = (unsigned int*)take((size_t)B * NCLS * GABLK * sizeof(unsigned int));
    int* nseeds        = (int*)take(B * NCLS * sizeof(int));
    unsigned long long* slots =
        (unsigned long long*)take((size_t)B * NCLS * SMAX * NSLOT * sizeof(unsigned long long));

    dim3 gA((N + 255) / 256, B);   // == (GABLK, B)
    k_setup<<<gA, 256, 0, stream>>>(logits, pts, offs, probs, sx, sy, sz,
                                    pcnt, pfst, (unsigned int*)slots, N);

    k_fps<<<BCPAD * FPS_SEG, FPS_T, 0, stream>>>(probs, sx, sy, sz, pcnt, pfst,
                                                 nseeds, seedxyz, slots, N);

    dim3 gC(N / 64, B);
    k_out<<<gC, 512, 0, stream>>>(probs, sx, sy, sz, nseeds, seedxyz, out, N);
}

// Round 9
// 64.160 us; speedup vs baseline: 1.2741x; 1.0245x over previous
//
#include <hip/hip_runtime.h>
#include <cstdint>

#define NCLS 13
#define SMAX 10
#define PTHRESH 0.05f
#define FPS_SEG 8        // blocks per (b,c)
#define FPS_T 512        // threads per FPS block (8 waves)
#define FPS_PPT 16       // points per thread: 8*512*16 = 65536
#define NSLOT 8          // one record per block per step
#define BCPAD 32         // padded bc dim: all 8 blocks of a bc share bid%32
#define GABLK 256        // k_setup blocks per batch (N/256)
#define BB 2             // batch
#define SLOT_DWORDS (BB * NCLS * SMAX * NSLOT * 2)

// Exact (un-fused) squared distance, matching numpy's ((dx*dx + dy*dy) + dz*dz) in f32.
__device__ __forceinline__ float d2f(float ax, float ay, float az,
                                     float bx, float by, float bz) {
    float dx = ax - bx;
    float dy = ay - by;
    float dz = az - bz;
    return __fadd_rn(__fadd_rn(__fmul_rn(dx, dx), __fmul_rn(dy, dy)), __fmul_rn(dz, dz));
}

// Monotone mapping float -> uint32. Never 0 for non-NaN input => key==0 means "empty".
__device__ __forceinline__ unsigned int fmono(float f) {
    unsigned int u = __float_as_uint(f);
    return (u & 0x80000000u) ? ~u : (u | 0x80000000u);
}

// Kernel A: class softmax, packed coords (float4) + per-point class-validity bitmask (u16),
// per-block partial counts/first-index (full overwrite, no atomics), FPS slot zeroing.
__global__ void k_setup(const float* __restrict__ logits, const float* __restrict__ pts,
                        const float* __restrict__ offs, float* __restrict__ probs,
                        float4* __restrict__ xyzw, unsigned short* __restrict__ vmask,
                        unsigned int* __restrict__ pcnt, unsigned int* __restrict__ pfst,
                        unsigned int* __restrict__ slots32, int N) {
    int b = blockIdx.y;
    int n = blockIdx.x * blockDim.x + threadIdx.x;
    int t = threadIdx.x;
    __shared__ unsigned int sC[NCLS], sF[NCLS];
    if (t < NCLS) { sC[t] = 0u; sF[t] = 0xFFFFFFFFu; }
    __syncthreads();

    // zero FPS slots (every call: graph replays leave stale nonzero keys behind)
    if (b == 0) {
        for (unsigned int i = blockIdx.x * blockDim.x + t; i < SLOT_DWORDS;
             i += GABLK * 256)
            slots32[i] = 0u;
    }

    if (n < N) {
        size_t bn = (size_t)b * N + n;
        const float* L = logits + bn * NCLS;
        float v[NCLS];
        float mx = -INFINITY;
#pragma unroll
        for (int c = 0; c < NCLS; ++c) { v[c] = L[c]; mx = fmaxf(mx, v[c]); }
        float s = 0.f;
#pragma unroll
        for (int c = 0; c < NCLS; ++c) { v[c] = expf(v[c] - mx); s += v[c]; }
        int lane = t & 63;
        int wave_base = n - lane;
        unsigned int msk = 0;
#pragma unroll
        for (int c = 0; c < NCLS; ++c) {
            float p = v[c] / s;
            probs[((size_t)b * NCLS + c) * N + n] = p;
            bool valid = p > PTHRESH;
            if (valid) msk |= (1u << c);
            unsigned long long m = __ballot(valid);
            if (lane == 0 && m) {
                atomicAdd(&sC[c], (unsigned int)__popcll(m));
                atomicMin(&sF[c], (unsigned int)(wave_base + __ffsll(m) - 1));
            }
        }
        float x = pts[bn * 3 + 0] + offs[bn * 3 + 0];
        float y = pts[bn * 3 + 1] + offs[bn * 3 + 1];
        float z = pts[bn * 3 + 2] + offs[bn * 3 + 2];
        xyzw[bn] = make_float4(x, y, z, 0.f);
        vmask[bn] = (unsigned short)msk;
    }
    __syncthreads();
    if (t < NCLS) {
        pcnt[(b * NCLS + t) * GABLK + blockIdx.x] = sC[t];
        pfst[(b * NCLS + t) * GABLK + blockIdx.x] = sF[t];
    }
}

// Kernel B: deterministic FPS. 8 blocks x 512 threads per (b,c). Per step (ONE barrier):
// wave butterfly argmax -> s_keys[parity] -> barrier -> wave0 reduces 8 keys, lane0
// publishes block record -> ALL waves poll the 8-slot line directly (8-lane coalesced
// relaxed load, no sleep) -> butterfly-8 + broadcast -> winner coords from immutable
// xyzw (single dwordx4). s_keys double-buffered on step parity (reuse separated by
// two barriers). Round 8's LDS s_win broadcast + 2 extra barriers are gone.
__global__ __launch_bounds__(FPS_T, 1) void k_fps(
    const float4* __restrict__ xyzw, const unsigned short* __restrict__ vmask,
    const unsigned int* __restrict__ pcnt, const unsigned int* __restrict__ pfst,
    int* __restrict__ nseeds, float* __restrict__ seedxyz,
    unsigned long long* __restrict__ slots, int N) {
    int bid = blockIdx.x;
    int bc = bid & (BCPAD - 1);
    int g = bid >> 5;             // segment 0..7
    if (bc >= BB * NCLS) return;  // padding blocks
    int b = bc / NCLS;
    int c = bc - b * NCLS;
    int t = threadIdx.x, lane = t & 63, w = t >> 6;

    // Reduce per-block partials (each wave redundantly; identical ops -> identical result)
    const unsigned int* pc = pcnt + (size_t)bc * GABLK;
    const unsigned int* pf = pfst + (size_t)bc * GABLK;
    uint4 c4 = *(const uint4*)(pc + lane * 4);
    uint4 f4 = *(const uint4*)(pf + lane * 4);
    unsigned int cnt = c4.x + c4.y + c4.z + c4.w;
    unsigned int fst = min(min(f4.x, f4.y), min(f4.z, f4.w));
#pragma unroll
    for (int off = 1; off < 64; off <<= 1) {
        cnt += __shfl_xor(cnt, off, 64);
        fst = min(fst, __shfl_xor(fst, off, 64));
    }
    int ns = min(SMAX, min((int)cnt / 50, (int)cnt));
    if (g == 0 && t == 0) nseeds[bc] = ns;
    if (ns == 0) return;

    const float4* P4 = xyzw + (size_t)b * N;
    const unsigned short* VM = vmask + (size_t)b * N;

    int base = g * (FPS_T * FPS_PPT) + t;
    float X[FPS_PPT], Y[FPS_PPT], Z[FPS_PPT], m[FPS_PPT];
    unsigned int vm = 0;
#pragma unroll
    for (int j = 0; j < FPS_PPT; ++j) {
        int n = base + (j << 9);
        float4 q = P4[n];
        X[j] = q.x; Y[j] = q.y; Z[j] = q.z;
        if ((VM[n] >> c) & 1) vm |= (1u << j);
        m[j] = INFINITY;
    }

    int st = (int)fst;
    float4 q0 = P4[st];
    float cx = q0.x, cy = q0.y, cz = q0.z;
    if (g == 0 && t == 0) {
        float* sd = seedxyz + (size_t)bc * SMAX * 3;
        sd[0] = cx; sd[1] = cy; sd[2] = cz;
    }

    __shared__ unsigned long long s_keys[2][FPS_T / 64];

    for (int s = 1; s < ns; ++s) {
        float best = -INFINITY;
        int bidx = 0;
#pragma unroll
        for (int j = 0; j < FPS_PPT; ++j) {   // ascending n => first-occurrence tiebreak
            int n = base + (j << 9);
            float d2 = d2f(X[j], Y[j], Z[j], cx, cy, cz);
            float add = ((vm >> j) & 1u) ? 0.0f : -INFINITY;
            float nm = fminf(m[j], __fadd_rn(d2, add));
            m[j] = nm;
            if (nm > best) { best = nm; bidx = n; }
        }
        unsigned long long key =
            ((unsigned long long)fmono(best) << 32) | (unsigned int)(~(unsigned int)bidx);
#pragma unroll
        for (int off = 1; off < 64; off <<= 1) {
            unsigned long long ok = __shfl_xor(key, off, 64);
            if (ok > key) key = ok;
        }
        int par = s & 1;
        if (lane == 0) s_keys[par][w] = key;
        __syncthreads();

        unsigned long long* sl = slots + ((size_t)bc * SMAX + s) * NSLOT;
        if (w == 0) {
            unsigned long long bk = (lane < 8) ? s_keys[par][lane] : 0ULL;
#pragma unroll
            for (int off = 1; off < 8; off <<= 1) {
                unsigned long long ok = __shfl_xor(bk, off, 8);
                if (ok > bk) bk = ok;
            }
            if (lane == 0)
                __hip_atomic_store(&sl[g], bk, __ATOMIC_RELAXED, __HIP_MEMORY_SCOPE_AGENT);
        }
        asm volatile("" ::: "memory");
        unsigned long long kk = 0ULL;
        while (true) {
            if (lane < NSLOT && kk == 0ULL)
                kk = __hip_atomic_load(&sl[lane], __ATOMIC_RELAXED,
                                       __HIP_MEMORY_SCOPE_AGENT);
            if (__all(kk != 0ULL || lane >= NSLOT)) break;
        }
        asm volatile("" ::: "memory");
#pragma unroll
        for (int off = 1; off < 8; off <<= 1) {
            unsigned long long ok = __shfl_xor(kk, off, 8);
            if (ok > kk) kk = ok;
        }
        kk = __shfl(kk, 0, 64);   // broadcast winner to all 64 lanes

        int widx = (int)(~(unsigned int)kk);
        float4 qw = P4[widx];
        cx = qw.x; cy = qw.y; cz = qw.z;
        if (g == 0 && t == 0) {
            float* sd = seedxyz + ((size_t)bc * SMAX + s) * 3;
            sd[0] = cx; sd[1] = cy; sd[2] = cz;
        }
    }
}

// Kernel C: 512-thread block owns 128 points (2 per lane). Wave w handles classes
// {w, w+8} in pass 1 (gd + partial sumexp -> LDS), rows k==w (mod 8) in pass 2 with
// float2 output stores (512B per wave-row write).
__global__ __launch_bounds__(512) void k_out(
    const float* __restrict__ probs, const float4* __restrict__ xyzw,
    const int* __restrict__ nseeds, const float* __restrict__ seedxyz,
    float* __restrict__ out, int N) {
    int b = blockIdx.y;
    int t = threadIdx.x;
    int lane = t & 63;
    int wv = t >> 6;
    int n0 = blockIdx.x * 128 + lane * 2;

    __shared__ float S[NCLS * SMAX * 3];
    __shared__ int NSs[NCLS];
    __shared__ float gdS[NCLS][128];
    __shared__ float psum[8][128];
    if (t < NCLS * SMAX * 3) S[t] = seedxyz[(size_t)b * NCLS * SMAX * 3 + t];
    if (t >= 448 && t < 448 + NCLS) NSs[t - 448] = nseeds[b * NCLS + (t - 448)];
    __syncthreads();

    float4 q0 = xyzw[(size_t)b * N + n0];
    float4 q1 = xyzw[(size_t)b * N + n0 + 1];

    const float kinv = 22.2222222f;   // 1/0.045
    float ps0 = 0.f, ps1 = 0.f;
#pragma unroll
    for (int c = wv; c < NCLS; c += 8) {
        int ns = NSs[c];
        float gdv0 = 0.f, gdv1 = 0.f;
        if (ns > 0) {
            float2 pv = *(const float2*)(probs + ((size_t)b * NCLS + c) * N + n0);
            if (pv.x > PTHRESH) {
                float wb[SMAX]; float sw = 0.f;
#pragma unroll
                for (int s = 0; s < SMAX; ++s) {
                    wb[s] = 0.f;
                    if (s < ns) {
                        const float* sd = &S[(c * SMAX + s) * 3];
                        float d2 = d2f(q0.x, q0.y, q0.z, sd[0], sd[1], sd[2]);
                        wb[s] = __expf(-d2 * kinv);
                        sw += wb[s];
                    }
                }
                gdv0 = __fdividef(pv.x, sw + 1e-8f);
#pragma unroll
                for (int s = 0; s < SMAX; ++s)
                    if (s < ns) ps0 += __expf(10.f * wb[s] * gdv0);
            } else {
                ps0 += (float)ns;   // exp(0)=1 per valid seed, exact
            }
            if (pv.y > PTHRESH) {
                float wb[SMAX]; float sw = 0.f;
#pragma unroll
                for (int s = 0; s < SMAX; ++s) {
                    wb[s] = 0.f;
                    if (s < ns) {
                        const float* sd = &S[(c * SMAX + s) * 3];
                        float d2 = d2f(q1.x, q1.y, q1.z, sd[0], sd[1], sd[2]);
                        wb[s] = __expf(-d2 * kinv);
                        sw += wb[s];
                    }
                }
                gdv1 = __fdividef(pv.y, sw + 1e-8f);
#pragma unroll
                for (int s = 0; s < SMAX; ++s)
                    if (s < ns) ps1 += __expf(10.f * wb[s] * gdv1);
            } else {
                ps1 += (float)ns;
            }
        }
        gdS[c][lane * 2] = gdv0;
        gdS[c][lane * 2 + 1] = gdv1;
    }
    psum[wv][lane * 2] = ps0;
    psum[wv][lane * 2 + 1] = ps1;
    __syncthreads();

    float tot0 = 0.f, tot1 = 0.f;
#pragma unroll
    for (int w = 0; w < 8; ++w) {
        tot0 += psum[w][lane * 2];
        tot1 += psum[w][lane * 2 + 1];
    }
    float inv0 = __fdividef(1.f, tot0);
    float inv1 = __fdividef(1.f, tot1);

    float* ob = out + (size_t)b * (NCLS * SMAX) * N + n0;
#pragma unroll
    for (int k = 0; k < NCLS * SMAX; k += 8) {
        int kk = k + wv;
        if (kk >= NCLS * SMAX) break;
        int c = kk / SMAX, s = kk - c * SMAX;
        float o0 = 0.f, o1 = 0.f;
        if (s < NSs[c]) {
            float g0 = gdS[c][lane * 2];
            float g1 = gdS[c][lane * 2 + 1];
            const float* sd = &S[(c * SMAX + s) * 3];
            if (g0 > 0.f) {
                float d2 = d2f(q0.x, q0.y, q0.z, sd[0], sd[1], sd[2]);
                o0 = __expf(10.f * __expf(-d2 * kinv) * g0) * inv0;
            } else {
                o0 = inv0;
            }
            if (g1 > 0.f) {
                float d2 = d2f(q1.x, q1.y, q1.z, sd[0], sd[1], sd[2]);
                o1 = __expf(10.f * __expf(-d2 * kinv) * g1) * inv1;
            } else {
                o1 = inv1;
            }
        }
        float2 st; st.x = o0; st.y = o1;
        *(float2*)(ob + (size_t)kk * N) = st;
    }
}

extern "C" void kernel_launch(void* const* d_in, const int* in_sizes, int n_in,
                              void* d_out, int out_size, void* d_ws, size_t ws_size,
                              hipStream_t stream) {
    const float* logits = (const float*)d_in[0];
    const float* pts    = (const float*)d_in[1];
    const float* offs   = (const float*)d_in[2];
    float* out = (float*)d_out;

    const int B = BB;
    const int BN = in_sizes[0] / NCLS;   // B*N
    const int N = BN / B;                // 65536

    // Workspace layout
    char* w = (char*)d_ws;
    size_t off = 0;
    auto take = [&](size_t bytes) -> void* {
        void* p = w + off;
        off = (off + bytes + 255) & ~(size_t)255;
        return p;
    };
    float* probs   = (float*)take((size_t)B * NCLS * N * sizeof(float));
    float4* xyzw   = (float4*)take((size_t)B * N * sizeof(float4));
    unsigned short* vmsk = (unsigned short*)take((size_t)B * N * sizeof(unsigned short));
    float* seedxyz = (float*)take((size_t)B * NCLS * SMAX * 3 * sizeof(float));
    unsigned int* pcnt = (unsigned int*)take((size_t)B * NCLS * GABLK * sizeof(unsigned int));
    unsigned int* pfst = (unsigned int*)take((size_t)B * NCLS * GABLK * sizeof(unsigned int));
    int* nseeds        = (int*)take(B * NCLS * sizeof(int));
    unsigned long long* slots =
        (unsigned long long*)take((size_t)B * NCLS * SMAX * NSLOT * sizeof(unsigned long long));

    dim3 gA((N + 255) / 256, B);   // == (GABLK, B)
    k_setup<<<gA, 256, 0, stream>>>(logits, pts, offs, probs, xyzw, vmsk,
                                    pcnt, pfst, (unsigned int*)slots, N);

    k_fps<<<BCPAD * FPS_SEG, FPS_T, 0, stream>>>(xyzw, vmsk, pcnt, pfst,
                                                 nseeds, seedxyz, slots, N);

    dim3 gC(N / 128, B);
    k_out<<<gC, 512, 0, stream>>>(probs, xyzw, nseeds, seedxyz, out, N);
}